// Round 4
// baseline (81.749 us; speedup 1.0000x reference)
//
#include <hip/hip_runtime.h>

#define BS 8
#define B2 16
#define S 2048
#define H 2048
#define PAD_ID 0

constexpr int BLOCKS_PER_PAIR = 128;
constexpr int WAVES_PER_BLOCK = 4;
constexpr int S_PER_WAVE = S / (BLOCKS_PER_PAIR * WAVES_PER_BLOCK); // 4
constexpr int TOTAL_BLOCKS = BS * BLOCKS_PER_PAIR;

// ws layout: [0] int counter (memset to 0 each launch)
//            [64..] int idxbuf[BS*2] (div, end)
//            [256..] float partial[BS*128]

__global__ __launch_bounds__(256) void fused_kernel(
    const float* __restrict__ hidden,    // [B2, S, H]
    const int*   __restrict__ input_ids, // [B2, S]
    const float* __restrict__ unsafe,    // [BS]
    const int*   __restrict__ risk_type, // [BS]
    const float* __restrict__ emb,       // [N_RISK, H]
    const float* __restrict__ v_w,       // [H]
    int*   __restrict__ counter,
    int*   __restrict__ idxbuf,
    float* __restrict__ partial,
    float* __restrict__ out)             // [17]
{
    const int b    = blockIdx.x / BLOCKS_PER_PAIR;
    const int blk  = blockIdx.x % BLOCKS_PER_PAIR;
    const int wave = threadIdx.x >> 6;
    const int lane = threadIdx.x & 63;
    const int rt   = risk_type[b];

    // --- combined per-lane weights (emb row + v_w are L1/L2-resident) ---
    float4 w[8];
    {
        const float4* embv = (const float4*)(emb + (size_t)rt * H);
        const float4* vwv  = (const float4*)v_w;
#pragma unroll
        for (int c = 0; c < 8; ++c) {
            int i = c * 64 + lane;
            float4 e = embv[i];
            float4 v = vwv[i];
            w[c] = make_float4(e.x * v.x, e.y * v.y, e.z * v.z, e.w * v.w);
        }
    }

    // --- in-block ids scan (16 KB, L2-broadcast across blocks of this pair) ---
    int my_cind = S, my_rind = S, my_div = S;
    {
        const int4* cid4 = (const int4*)(input_ids + b * S);
        const int4* rid4 = (const int4*)(input_ids + (b + BS) * S);
        for (int i = threadIdx.x; i < S / 4; i += 256) {
            int4 c4 = cid4[i];
            int4 r4 = rid4[i];
            int base = i * 4;
            int cv[4] = {c4.x, c4.y, c4.z, c4.w};
            int rv[4] = {r4.x, r4.y, r4.z, r4.w};
#pragma unroll
            for (int j = 0; j < 4; ++j) {
                int s = base + j;
                if (cv[j] == PAD_ID && s < my_cind) my_cind = s;
                if (rv[j] == PAD_ID && s < my_rind) my_rind = s;
                if (cv[j] != rv[j]  && s < my_div)  my_div  = s;
            }
        }
#pragma unroll
        for (int off = 32; off > 0; off >>= 1) {
            my_cind = min(my_cind, __shfl_xor(my_cind, off, 64));
            my_rind = min(my_rind, __shfl_xor(my_rind, off, 64));
            my_div  = min(my_div,  __shfl_xor(my_div,  off, 64));
        }
    }
    __shared__ int s_c[WAVES_PER_BLOCK], s_r[WAVES_PER_BLOCK], s_d[WAVES_PER_BLOCK];
    if (lane == 0) { s_c[wave] = my_cind; s_r[wave] = my_rind; s_d[wave] = my_div; }
    __syncthreads();
    const int c_ind = min(min(s_c[0], s_c[1]), min(s_c[2], s_c[3]));
    const int r_pad = min(min(s_r[0], s_r[1]), min(s_r[2], s_r[3]));
    const int fdiv  = min(min(s_d[0], s_d[1]), min(s_d[2], s_d[3]));
    const bool has_div = (fdiv < S);
    const int dv    = has_div ? fdiv : (S - 1);
    const int end   = has_div ? max(c_ind, r_pad) : S;
    const int r_ind = has_div ? r_pad : c_ind;
    const float u   = unsafe[b];

    // --- streaming paired dot products + fused hinge ---
    const float4* hc = (const float4*)(hidden + (size_t)b * S * H);
    const float4* hr = (const float4*)(hidden + (size_t)(b + BS) * S * H);
    const int s0 = (blk * WAVES_PER_BLOCK + wave) * S_PER_WAVE;
    float hinge = 0.f;

#pragma unroll
    for (int r = 0; r < S_PER_WAVE; ++r) {
        const int s = s0 + r;
        const float4* rc = hc + (size_t)s * (H / 4);
        const float4* rr = hr + (size_t)s * (H / 4);
        float ac = 0.f, ar = 0.f;
#pragma unroll
        for (int c = 0; c < 8; ++c) {
            float4 x = rc[c * 64 + lane];
            float4 y = rr[c * 64 + lane];
            ac += x.x * w[c].x + x.y * w[c].y + x.z * w[c].z + x.w * w[c].w;
            ar += y.x * w[c].x + y.y * w[c].y + y.z * w[c].z + y.w * w[c].w;
        }
#pragma unroll
        for (int off = 32; off > 0; off >>= 1) {
            ac += __shfl_xor(ac, off, 64);
            ar += __shfl_xor(ar, off, 64);
        }
        if (lane == 0) {
            if (s >= dv && s < end) {
                float h = u - (ac - ar);
                hinge += (h > 0.f) ? h : 0.f;
            }
            if (s == c_ind - 1) out[1 + b] = ac;
            if (s == r_ind - 1) out[9 + b] = ar;
        }
    }

    __shared__ float s_h[WAVES_PER_BLOCK];
    __shared__ int s_last;
    if (lane == 0) s_h[wave] = hinge;
    __syncthreads();

    if (threadIdx.x == 0) {
        partial[b * BLOCKS_PER_PAIR + blk] = (s_h[0] + s_h[1]) + (s_h[2] + s_h[3]);
        if (blk == 0) { idxbuf[b * 2] = dv; idxbuf[b * 2 + 1] = end; }
        __threadfence();                       // make partial/idx visible device-wide
        int old = atomicAdd(counter, 1);       // device-scope by default
        s_last = (old == TOTAL_BLOCKS - 1);
    }
    __syncthreads();

    if (s_last) {
        __threadfence();                       // acquire side
        if (threadIdx.x < 64) {                // wave 0 does fixed-order reduce
            float t = 0.f;
            for (int bb = 0; bb < BS; ++bb) {
                float ssum = partial[bb * BLOCKS_PER_PAIR + lane]
                           + partial[bb * BLOCKS_PER_PAIR + 64 + lane];
#pragma unroll
                for (int off = 32; off > 0; off >>= 1)
                    ssum += __shfl_xor(ssum, off, 64);
                int cnt = max(idxbuf[bb * 2 + 1] - idxbuf[bb * 2], 1);
                t += ssum / (float)cnt;
            }
            if (lane == 0) out[0] = t / (float)BS;
        }
    }
}

extern "C" void kernel_launch(void* const* d_in, const int* in_sizes, int n_in,
                              void* d_out, int out_size, void* d_ws, size_t ws_size,
                              hipStream_t stream) {
    const float* hidden    = (const float*)d_in[0];
    const int*   input_ids = (const int*)d_in[1];
    const float* unsafe    = (const float*)d_in[2];
    const int*   risk_type = (const int*)d_in[3];
    const float* emb       = (const float*)d_in[4];
    const float* v_w       = (const float*)d_in[5];
    float* out = (float*)d_out;

    int*   counter = (int*)d_ws;
    int*   idxbuf  = (int*)((char*)d_ws + 64);
    float* partial = (float*)((char*)d_ws + 256);

    hipMemsetAsync(counter, 0, sizeof(int), stream);   // ws not re-poisoned between replays
    fused_kernel<<<TOTAL_BLOCKS, 256, 0, stream>>>(
        hidden, input_ids, unsafe, risk_type, emb, v_w,
        counter, idxbuf, partial, out);
}

// Round 5
// 47.333 us; speedup vs baseline: 1.7271x; 1.7271x over previous
//
#include <hip/hip_runtime.h>

#define BS 8
#define B2 16
#define S 2048
#define H 2048
#define PAD_ID 0

constexpr int BLOCKS_PER_PAIR = 128;
constexpr int WAVES_PER_BLOCK = 4;
constexpr int S_PER_WAVE = S / (BLOCKS_PER_PAIR * WAVES_PER_BLOCK); // 4

// ws layout: [0..63]  int idxbuf[BS*2] (div, end) -- written by blk==0 of each pair
//            [256..]  float partial[BS*128]

// ---- Kernel 1: fused scan + paired dot products + hinge partials ----------
__global__ __launch_bounds__(256) void main_kernel(
    const float* __restrict__ hidden,    // [B2, S, H]
    const int*   __restrict__ input_ids, // [B2, S]
    const float* __restrict__ unsafe,    // [BS]
    const int*   __restrict__ risk_type, // [BS]
    const float* __restrict__ emb,       // [N_RISK, H]
    const float* __restrict__ v_w,       // [H]
    int*   __restrict__ idxbuf,          // [BS*2]
    float* __restrict__ partial,         // [BS*128]
    float* __restrict__ out)             // [17]
{
    const int b    = blockIdx.x / BLOCKS_PER_PAIR;
    const int blk  = blockIdx.x % BLOCKS_PER_PAIR;
    const int wave = threadIdx.x >> 6;
    const int lane = threadIdx.x & 63;
    const int rt   = risk_type[b];

    // --- combined per-lane weights (emb row + v_w are L1/L2-resident) ---
    float4 w[8];
    {
        const float4* embv = (const float4*)(emb + (size_t)rt * H);
        const float4* vwv  = (const float4*)v_w;
#pragma unroll
        for (int c = 0; c < 8; ++c) {
            int i = c * 64 + lane;
            float4 e = embv[i];
            float4 v = vwv[i];
            w[c] = make_float4(e.x * v.x, e.y * v.y, e.z * v.z, e.w * v.w);
        }
    }

    // --- in-block ids scan (2x8KB int4 loads, L2-resident across blocks) ---
    int my_cind = S, my_rind = S, my_div = S;
    {
        const int4* cid4 = (const int4*)(input_ids + b * S);
        const int4* rid4 = (const int4*)(input_ids + (b + BS) * S);
        for (int i = threadIdx.x; i < S / 4; i += 256) {
            int4 c4 = cid4[i];
            int4 r4 = rid4[i];
            int base = i * 4;
            int cv[4] = {c4.x, c4.y, c4.z, c4.w};
            int rv[4] = {r4.x, r4.y, r4.z, r4.w};
#pragma unroll
            for (int j = 0; j < 4; ++j) {
                int s = base + j;
                if (cv[j] == PAD_ID && s < my_cind) my_cind = s;
                if (rv[j] == PAD_ID && s < my_rind) my_rind = s;
                if (cv[j] != rv[j]  && s < my_div)  my_div  = s;
            }
        }
#pragma unroll
        for (int off = 32; off > 0; off >>= 1) {
            my_cind = min(my_cind, __shfl_xor(my_cind, off, 64));
            my_rind = min(my_rind, __shfl_xor(my_rind, off, 64));
            my_div  = min(my_div,  __shfl_xor(my_div,  off, 64));
        }
    }
    __shared__ int s_c[WAVES_PER_BLOCK], s_r[WAVES_PER_BLOCK], s_d[WAVES_PER_BLOCK];
    if (lane == 0) { s_c[wave] = my_cind; s_r[wave] = my_rind; s_d[wave] = my_div; }
    __syncthreads();
    const int c_ind = min(min(s_c[0], s_c[1]), min(s_c[2], s_c[3]));
    const int r_pad = min(min(s_r[0], s_r[1]), min(s_r[2], s_r[3]));
    const int fdiv  = min(min(s_d[0], s_d[1]), min(s_d[2], s_d[3]));
    const bool has_div = (fdiv < S);
    const int dv    = has_div ? fdiv : (S - 1);
    const int end   = has_div ? max(c_ind, r_pad) : S;
    const int r_ind = has_div ? r_pad : c_ind;
    const float u   = unsafe[b];

    // --- streaming paired dot products + fused hinge ---
    const float4* hc = (const float4*)(hidden + (size_t)b * S * H);
    const float4* hr = (const float4*)(hidden + (size_t)(b + BS) * S * H);
    const int s0 = (blk * WAVES_PER_BLOCK + wave) * S_PER_WAVE;
    float hinge = 0.f;

#pragma unroll
    for (int r = 0; r < S_PER_WAVE; ++r) {
        const int s = s0 + r;
        const float4* rc = hc + (size_t)s * (H / 4);
        const float4* rr = hr + (size_t)s * (H / 4);
        float ac = 0.f, ar = 0.f;
#pragma unroll
        for (int c = 0; c < 8; ++c) {
            float4 x = rc[c * 64 + lane];
            float4 y = rr[c * 64 + lane];
            ac += x.x * w[c].x + x.y * w[c].y + x.z * w[c].z + x.w * w[c].w;
            ar += y.x * w[c].x + y.y * w[c].y + y.z * w[c].z + y.w * w[c].w;
        }
#pragma unroll
        for (int off = 32; off > 0; off >>= 1) {
            ac += __shfl_xor(ac, off, 64);
            ar += __shfl_xor(ar, off, 64);
        }
        if (lane == 0) {
            if (s >= dv && s < end) {
                float h = u - (ac - ar);
                hinge += (h > 0.f) ? h : 0.f;
            }
            if (s == c_ind - 1) out[1 + b] = ac;
            if (s == r_ind - 1) out[9 + b] = ar;
        }
    }

    __shared__ float s_h[WAVES_PER_BLOCK];
    if (lane == 0) s_h[wave] = hinge;
    __syncthreads();
    if (threadIdx.x == 0) {
        partial[b * BLOCKS_PER_PAIR + blk] = (s_h[0] + s_h[1]) + (s_h[2] + s_h[3]);
        if (blk == 0) { idxbuf[b * 2] = dv; idxbuf[b * 2 + 1] = end; }
    }
}

// ---- Kernel 2: deterministic loss reduction -------------------------------
__global__ __launch_bounds__(512) void loss_kernel(
    const float* __restrict__ partial, // [BS*128]
    const int*   __restrict__ idxbuf,  // [BS*2]
    float* __restrict__ out)           // [17]
{
    const int b    = threadIdx.x >> 6;
    const int lane = threadIdx.x & 63;
    float s = partial[b * BLOCKS_PER_PAIR + lane]
            + partial[b * BLOCKS_PER_PAIR + 64 + lane];
#pragma unroll
    for (int off = 32; off > 0; off >>= 1)
        s += __shfl_xor(s, off, 64);

    __shared__ float s_per[BS];
    if (lane == 0) {
        int cnt = max(idxbuf[b * 2 + 1] - idxbuf[b * 2], 1);
        s_per[b] = s / (float)cnt;
    }
    __syncthreads();
    if (threadIdx.x == 0) {
        float t = 0.f;
#pragma unroll
        for (int i = 0; i < BS; ++i) t += s_per[i];
        out[0] = t / (float)BS;
    }
}

extern "C" void kernel_launch(void* const* d_in, const int* in_sizes, int n_in,
                              void* d_out, int out_size, void* d_ws, size_t ws_size,
                              hipStream_t stream) {
    const float* hidden    = (const float*)d_in[0];
    const int*   input_ids = (const int*)d_in[1];
    const float* unsafe    = (const float*)d_in[2];
    const int*   risk_type = (const int*)d_in[3];
    const float* emb       = (const float*)d_in[4];
    const float* v_w       = (const float*)d_in[5];
    float* out = (float*)d_out;

    int*   idxbuf  = (int*)d_ws;
    float* partial = (float*)((char*)d_ws + 256);

    main_kernel<<<BS * BLOCKS_PER_PAIR, 256, 0, stream>>>(
        hidden, input_ids, unsafe, risk_type, emb, v_w, idxbuf, partial, out);
    loss_kernel<<<1, 512, 0, stream>>>(partial, idxbuf, out);
}